// Round 3
// baseline (373.895 us; speedup 1.0000x reference)
//
#include <hip/hip_runtime.h>

#define Bsz 8
#define Nn  512
#define Dd  768
#define Ll  16

#define SPAN_BLOCKS 2048
#define PREP_BLOCKS (Bsz * (Nn / 8))   // 512

// ws layout (floats): At[65536] | Bt[65536] | se_part[512] | pb[SPAN_BLOCKS*8]
// pb[blk*8 + {0:tp,1:tn,2:fp,3:valc,4:span_loss_sum}]  -- plain stores, NO atomics

// ---------------------------------------------------------------------------
// Kernel 1: per 8-row group of x, compute all 64 dot products (32 se cols,
// 16 a-cols, 16 bb-cols), do the start/end focal loss inline, store At/Bt
// transposed to [ (b*L+l)*N + n ] for coalesced reads in kernel 2.
// ---------------------------------------------------------------------------
__global__ __launch_bounds__(256) void k_prep(
    const float* __restrict__ x, const float* __restrict__ start,
    const float* __restrict__ end, const int* __restrict__ seqlen,
    const float* __restrict__ W_se, const float* __restrict__ b_se,
    const float* __restrict__ W_span, const float* __restrict__ b_span,
    float* __restrict__ At, float* __restrict__ Bt, float* __restrict__ se_part)
{
    __shared__ float xs[8 * Dd];        // 24 KB
    __shared__ float part[256 * 8];     // 8 KB
    __shared__ float s_se;

    const int tid = threadIdx.x;
    const int blk = blockIdx.x;         // 512 blocks: b*64 + group
    const int b   = blk >> 6;
    const int n0  = (blk & 63) * 8;

    if (tid == 0) s_se = 0.0f;

    const float4* xsrc = (const float4*)(x + (size_t)(b * Nn + n0) * Dd);
    float4* xd = (float4*)xs;
    for (int i = tid; i < 8 * Dd / 4; i += 256) xd[i] = xsrc[i];
    __syncthreads();

    const int c = tid & 63;   // column 0..63
    const int q = tid >> 6;   // k-quarter 0..3

    float a8[8];
#pragma unroll
    for (int r = 0; r < 8; ++r) a8[r] = 0.0f;

    const float* w;
    int stride;
    if (c < 32)       { w = W_se + c;                    stride = 32; }
    else if (c < 48)  { w = W_span + (c - 32);           stride = 16; }
    else              { w = W_span + Dd * 16 + (c - 48); stride = 16; }

    const int k0 = q * 192;
#pragma unroll 4
    for (int k = k0; k < k0 + 192; ++k) {
        const float wv = w[(size_t)k * stride];
#pragma unroll
        for (int r = 0; r < 8; ++r) a8[r] += xs[r * Dd + k] * wv;
    }
#pragma unroll
    for (int r = 0; r < 8; ++r) part[tid * 8 + r] = a8[r];
    __syncthreads();

    if (tid < 64) {
        float z[8];
#pragma unroll
        for (int r = 0; r < 8; ++r)
            z[r] = part[c * 8 + r] + part[(c + 64) * 8 + r] +
                   part[(c + 128) * 8 + r] + part[(c + 192) * 8 + r];

        if (c < 32) {
            // start,end are [B, L, N]: batch stride Ll*Nn
            const int sl = seqlen[b];
            float lsum = 0.0f;
            const float bse = b_se[c];
#pragma unroll
            for (int r = 0; r < 8; ++r) {
                const int n = n0 + r;
                const float zz = z[r] + bse;
                const float p = 1.0f / (1.0f + __expf(-zz));
                const float y = (c < 16) ? start[(b * Ll + c) * Nn + n]
                                         : end[(b * Ll + (c - 16)) * Nn + n];
                const float fl = (y == 1.0f)
                    ? (-0.5f * (1.0f - p) * (1.0f - p) * __logf(p))
                    : (-0.5f * p * p * __logf(1.0f - p));
                if (n < sl) lsum += fl;
            }
            atomicAdd(&s_se, lsum);   // LDS atomic, 32 per block — cheap
        } else if (c < 48) {
            const int l = c - 32;
            const float bsp = b_span[l];
#pragma unroll
            for (int r = 0; r < 8; ++r)
                At[(b * Ll + l) * Nn + n0 + r] = z[r] + bsp;  // bias folded in
        } else {
            const int l = c - 48;
#pragma unroll
            for (int r = 0; r < 8; ++r)
                Bt[(b * Ll + l) * Nn + n0 + r] = z[r];
        }
    }
    __syncthreads();
    if (tid == 0) se_part[blk] = s_se;   // plain store, distinct address per block
}

// ---------------------------------------------------------------------------
// Kernel 2: the big [B,L,N,N] pass. 2048 blocks x 256 threads x 16 float4
// items, FORCED software pipeline (round-2's source-level version was
// silently re-serialized by the scheduler: VGPR stayed 32).
//
// Per stage: (1) issue At/Bt loads needed NOW, (2) sched_barrier,
// (3) issue span/val loads for stage s+1 (prefetch — issued YOUNGER than
// the At/Bt loads so the compute's vmcnt wait does not drain them; vmcnt
// is FIFO), (4) sched_barrier, (5) compute + store. Steady state keeps 2
// HBM loads in flight per wave across every compute phase.
//
// Plain stores (nt experiment regressed 13%: stores were NOT the evictor,
// FETCH unchanged, and nt degraded the store path).
//
// focal closed form: z = logit; t = (span==1)? z : -z; u=e^{-t}; d=1+u;
//   focal = 0.5 * (u/d)^2 * log d
// ---------------------------------------------------------------------------
__global__ __launch_bounds__(256) void k_span(
    const float* __restrict__ At, const float* __restrict__ Bt,
    const int* __restrict__ span, const int* __restrict__ val,
    float* __restrict__ out, float* __restrict__ pb)
{
    const int tid = threadIdx.x;
    const int base0 = blockIdx.x * (256 * 16) + tid;   // float4-item index

    const int4*  s4 = (const int4*)span;
    const int4*  v4 = (const int4*)val;
    float4*      o4 = (float4*)out;

    int tpc = 0, tnc = 0, fpc = 0, vc = 0;
    float ls = 0.0f;

#define DO_ELEM(aa, btj, spv, vvv, pout)                                      \
    {                                                                         \
        const float z = (aa) + (btj);                                         \
        const int pred = (z > 0.0f) ? 1 : 0;                                  \
        (pout) = pred ? 1.0f : 0.0f;                                          \
        tpc += ((spv) == 1) & pred;                                           \
        tnc += ((spv) == 1) & (pred ^ 1);                                     \
        fpc += ((spv) == 0) & ((vvv) == 1) & pred;                            \
        vc  += (vvv);                                                         \
        const float t = ((spv) == 1) ? z : -z;                                \
        const float u = __expf(-t);                                           \
        const float d = 1.0f + u;                                             \
        const float m = u * __builtin_amdgcn_rcpf(d);                         \
        const float fl = 0.5f * m * m * __logf(d);                            \
        ls += (vvv) ? fl : 0.0f;                                              \
    }

    // prologue: stage 0's span/val
    int4 csp = s4[base0], cvv = v4[base0];

#pragma unroll
    for (int st = 0; st < 16; ++st) {
        const int vid = base0 + st * 256;

        // (1) loads the CURRENT stage's compute waits on — issued oldest
        const int ri = vid >> 7;                         // (b*L+l)*N + i
        const float  av = At[ri];
        const float4 bt = *(const float4*)(Bt + ((ri >> 9) << 9) + ((vid & 127) << 2));
        __builtin_amdgcn_sched_barrier(0);

        // (2) prefetch stage st+1's HBM streams — issued YOUNGER, so the
        // wait for av/bt (vmcnt FIFO) leaves these in flight
        int4 nsp, nvv;
        if (st < 15) { nsp = s4[vid + 256]; nvv = v4[vid + 256]; }
        __builtin_amdgcn_sched_barrier(0);

        // (3) compute + store
        float4 po;
        DO_ELEM(av, bt.x, csp.x, cvv.x, po.x)
        DO_ELEM(av, bt.y, csp.y, cvv.y, po.y)
        DO_ELEM(av, bt.z, csp.z, cvv.z, po.z)
        DO_ELEM(av, bt.w, csp.w, cvv.w, po.w)
        o4[vid] = po;

        if (st < 15) { csp = nsp; cvv = nvv; }
    }
#undef DO_ELEM

    // wave (64-lane) reduction
    for (int off = 32; off; off >>= 1) {
        tpc += __shfl_down(tpc, off);
        tnc += __shfl_down(tnc, off);
        fpc += __shfl_down(fpc, off);
        vc  += __shfl_down(vc,  off);
        ls  += __shfl_down(ls,  off);
    }

    __shared__ int   si[4][4];
    __shared__ float sf[4];
    const int wave = tid >> 6, lane = tid & 63;
    if (lane == 0) {
        si[wave][0] = tpc; si[wave][1] = tnc; si[wave][2] = fpc; si[wave][3] = vc;
        sf[wave] = ls;
    }
    __syncthreads();
    if (tid == 0) {
        int t0 = 0, t1 = 0, t2 = 0, t3 = 0;
        float f = 0.0f;
        for (int w = 0; w < 4; ++w) {
            t0 += si[w][0]; t1 += si[w][1]; t2 += si[w][2]; t3 += si[w][3];
            f += sf[w];
        }
        float* dst = pb + blockIdx.x * 8;
        dst[0] = (float)t0;   // counts <= 16384/block: exact in float
        dst[1] = (float)t1;
        dst[2] = (float)t2;
        dst[3] = (float)t3;
        dst[4] = f;
    }
}

// ---------------------------------------------------------------------------
// Kernel 3: reduce per-block partials and finalize the 5 scalar outputs
// ---------------------------------------------------------------------------
__global__ __launch_bounds__(256) void k_fin(
    const float* __restrict__ pb, const float* __restrict__ se_part,
    const int* __restrict__ seqlen, float* __restrict__ out5)
{
    const int tid = threadIdx.x;
    long long t0 = 0, t1 = 0, t2 = 0, t3 = 0;   // int accumulation: exact
    float f = 0.0f, se = 0.0f;

    for (int i = tid; i < SPAN_BLOCKS; i += 256) {
        const float4 p0 = *(const float4*)(pb + i * 8);
        const float  p4 = pb[i * 8 + 4];
        t0 += (long long)p0.x; t1 += (long long)p0.y;
        t2 += (long long)p0.z; t3 += (long long)p0.w;
        f  += p4;
    }
    for (int i = tid; i < PREP_BLOCKS; i += 256) se += se_part[i];

    // wave reduce
    for (int off = 32; off; off >>= 1) {
        t0 += __shfl_down(t0, off);
        t1 += __shfl_down(t1, off);
        t2 += __shfl_down(t2, off);
        t3 += __shfl_down(t3, off);
        f  += __shfl_down(f,  off);
        se += __shfl_down(se, off);
    }

    __shared__ long long sl[4][4];
    __shared__ float sfl[4][2];
    const int wave = tid >> 6, lane = tid & 63;
    if (lane == 0) {
        sl[wave][0] = t0; sl[wave][1] = t1; sl[wave][2] = t2; sl[wave][3] = t3;
        sfl[wave][0] = f; sfl[wave][1] = se;
    }
    __syncthreads();
    if (tid == 0) {
        long long a0 = 0, a1 = 0, a2 = 0, a3 = 0;
        float af = 0.0f, ase = 0.0f;
        for (int w = 0; w < 4; ++w) {
            a0 += sl[w][0]; a1 += sl[w][1]; a2 += sl[w][2]; a3 += sl[w][3];
            af += sfl[w][0]; ase += sfl[w][1];
        }
        int ssum = 0;
        for (int i = 0; i < Bsz; ++i) ssum += seqlen[i];
        out5[0] = (float)a0;                                   // tp
        out5[1] = (float)a1;                                   // tn
        out5[2] = (float)a2;                                   // fp
        out5[3] = ase / (2.0f * Ll * (float)ssum);             // startend_loss
        out5[4] = af / ((float)a3 + 1e-6f);                    // span_loss
    }
}

extern "C" void kernel_launch(void* const* d_in, const int* in_sizes, int n_in,
                              void* d_out, int out_size, void* d_ws, size_t ws_size,
                              hipStream_t stream) {
    const float* x      = (const float*)d_in[0];
    const float* start  = (const float*)d_in[1];
    const float* end    = (const float*)d_in[2];
    const int*   span   = (const int*)d_in[3];
    const int*   val    = (const int*)d_in[4];
    const int*   seqlen = (const int*)d_in[5];
    const float* W_se   = (const float*)d_in[6];
    const float* b_se   = (const float*)d_in[7];
    const float* W_span = (const float*)d_in[8];
    const float* b_span = (const float*)d_in[9];

    float* out = (float*)d_out;

    const size_t n_at = (size_t)Bsz * Ll * Nn;    // 65536
    float* At      = (float*)d_ws;
    float* Bt      = At + n_at;
    float* se_part = Bt + n_at;
    float* pb      = se_part + PREP_BLOCKS;

    k_prep<<<PREP_BLOCKS, 256, 0, stream>>>(x, start, end, seqlen,
                                            W_se, b_se, W_span, b_span,
                                            At, Bt, se_part);

    const long long total_elems = (long long)Bsz * Ll * Nn * Nn;   // 33554432
    k_span<<<SPAN_BLOCKS, 256, 0, stream>>>(At, Bt, span, val, out, pb);

    k_fin<<<1, 256, 0, stream>>>(pb, se_part, seqlen, out + total_elems);
}

// Round 4
// 371.677 us; speedup vs baseline: 1.0060x; 1.0060x over previous
//
#include <hip/hip_runtime.h>

#define Bsz 8
#define Nn  512
#define Dd  768
#define Ll  16

#define SPAN_BLOCKS 2048
#define PREP_BLOCKS (Bsz * (Nn / 8))   // 512

typedef int   i32x4 __attribute__((ext_vector_type(4)));
typedef float f32x4 __attribute__((ext_vector_type(4)));

// ws layout (floats): At[65536] | Bt[65536] | se_part[512] | pb[SPAN_BLOCKS*8]

// ---------------------------------------------------------------------------
// Kernel 1: unchanged.
// ---------------------------------------------------------------------------
__global__ __launch_bounds__(256) void k_prep(
    const float* __restrict__ x, const float* __restrict__ start,
    const float* __restrict__ end, const int* __restrict__ seqlen,
    const float* __restrict__ W_se, const float* __restrict__ b_se,
    const float* __restrict__ W_span, const float* __restrict__ b_span,
    float* __restrict__ At, float* __restrict__ Bt, float* __restrict__ se_part)
{
    __shared__ float xs[8 * Dd];        // 24 KB
    __shared__ float part[256 * 8];     // 8 KB
    __shared__ float s_se;

    const int tid = threadIdx.x;
    const int blk = blockIdx.x;         // 512 blocks: b*64 + group
    const int b   = blk >> 6;
    const int n0  = (blk & 63) * 8;

    if (tid == 0) s_se = 0.0f;

    const float4* xsrc = (const float4*)(x + (size_t)(b * Nn + n0) * Dd);
    float4* xd = (float4*)xs;
    for (int i = tid; i < 8 * Dd / 4; i += 256) xd[i] = xsrc[i];
    __syncthreads();

    const int c = tid & 63;   // column 0..63
    const int q = tid >> 6;   // k-quarter 0..3

    float a8[8];
#pragma unroll
    for (int r = 0; r < 8; ++r) a8[r] = 0.0f;

    const float* w;
    int stride;
    if (c < 32)       { w = W_se + c;                    stride = 32; }
    else if (c < 48)  { w = W_span + (c - 32);           stride = 16; }
    else              { w = W_span + Dd * 16 + (c - 48); stride = 16; }

    const int k0 = q * 192;
#pragma unroll 4
    for (int k = k0; k < k0 + 192; ++k) {
        const float wv = w[(size_t)k * stride];
#pragma unroll
        for (int r = 0; r < 8; ++r) a8[r] += xs[r * Dd + k] * wv;
    }
#pragma unroll
    for (int r = 0; r < 8; ++r) part[tid * 8 + r] = a8[r];
    __syncthreads();

    if (tid < 64) {
        float z[8];
#pragma unroll
        for (int r = 0; r < 8; ++r)
            z[r] = part[c * 8 + r] + part[(c + 64) * 8 + r] +
                   part[(c + 128) * 8 + r] + part[(c + 192) * 8 + r];

        if (c < 32) {
            const int sl = seqlen[b];
            float lsum = 0.0f;
            const float bse = b_se[c];
#pragma unroll
            for (int r = 0; r < 8; ++r) {
                const int n = n0 + r;
                const float zz = z[r] + bse;
                const float p = 1.0f / (1.0f + __expf(-zz));
                const float y = (c < 16) ? start[(b * Ll + c) * Nn + n]
                                         : end[(b * Ll + (c - 16)) * Nn + n];
                const float fl = (y == 1.0f)
                    ? (-0.5f * (1.0f - p) * (1.0f - p) * __logf(p))
                    : (-0.5f * p * p * __logf(1.0f - p));
                if (n < sl) lsum += fl;
            }
            atomicAdd(&s_se, lsum);
        } else if (c < 48) {
            const int l = c - 32;
            const float bsp = b_span[l];
#pragma unroll
            for (int r = 0; r < 8; ++r)
                At[(b * Ll + l) * Nn + n0 + r] = z[r] + bsp;  // bias folded in
        } else {
            const int l = c - 48;
#pragma unroll
            for (int r = 0; r < 8; ++r)
                Bt[(b * Ll + l) * Nn + n0 + r] = z[r];
        }
    }
    __syncthreads();
    if (tid == 0) se_part[blk] = s_se;
}

// ---------------------------------------------------------------------------
// Kernel 2: hand-pipelined with inline-asm loads + counted vmcnt (T4).
// The compiler kept re-serializing compiler-visible prefetches (VGPR 28-32
// across 3 schedule attempts); asm loads cannot be sunk.
//
// Per-thread streams (per stage s of 16): sp/vv = span/val int4 (HBM),
// av = At scalar (cache), bt = Bt float4 (LOOP-INVARIANT per thread --
// j and (b,l) are constant within a block), store out float4.
// All in-loop vmem is volatile asm; shared 32-bit voffset per stream
// (+4096 B/stage), av via imm offset:8*(s+2).
//
// Pipeline: sp/vv prefetch distance 3 (ring 3), av distance 2 (ring 2),
// po ring 3 (WAR vs in-flight store). Issue order per stage:
//   [wait vmcnt(K)] [compute s] [load av(s+2)] [load sp/vv(s+3)] [store s]
// Stores count in vmcnt on CDNA -- included in K.
// K = {3,6,7,7,7,7,7,7,7,7,7,7,7,7,5,2} (hand-derived, see session notes).
// ---------------------------------------------------------------------------
__global__ __launch_bounds__(256) void k_span(
    const float* __restrict__ At, const float* __restrict__ Bt,
    const int* __restrict__ span, const int* __restrict__ val,
    float* __restrict__ out, float* __restrict__ pb)
{
    const int tid = threadIdx.x;
    const int base0 = blockIdx.x * (256 * 16) + tid;   // float4-item index

    int tpc = 0, tnc = 0, fpc = 0, vc = 0;
    float ls = 0.0f;

    unsigned voff_pf = (unsigned)base0 * 16u;                 // span/val/out byte offset
    unsigned voff_st = voff_pf;
    const int ri0 = base0 >> 7;
    const unsigned voff_av = (unsigned)ri0 << 2;              // At byte offset (stage 0)
    const unsigned voff_bt = (((unsigned)base0 >> 16) << 11)  // Bt byte offset (invariant)
                           | (((unsigned)base0 & 127u) << 4);

    i32x4 sp0, sp1, sp2, vv0, vv1, vv2;
    float av0, av1;
    f32x4 bt, po0, po1, po2;

#define LD_BT() \
    asm volatile("global_load_dwordx4 %0, %1, %2" \
                 : "=v"(bt) : "v"(voff_bt), "s"(Bt) : "memory");

#define LD_SPVV(SPX, VVX) \
    asm volatile("global_load_dwordx4 %0, %2, %3\n\t" \
                 "global_load_dwordx4 %1, %2, %4" \
                 : "=v"(SPX), "=v"(VVX) \
                 : "v"(voff_pf), "s"(span), "s"(val) : "memory"); \
    voff_pf += 4096u;

#define LD_AV(AVX, OFFSTR) \
    asm volatile("global_load_dword %0, %1, %2 offset:" OFFSTR \
                 : "=v"(AVX) : "v"(voff_av), "s"(At) : "memory");

#define ST_OUT(POX) \
    asm volatile("global_store_dwordx4 %0, %1, %2" \
                 :: "v"(voff_st), "v"(POX), "s"(out) : "memory"); \
    voff_st += 4096u;

#define WAITK(KSTR) \
    asm volatile("s_waitcnt vmcnt(" KSTR ")" ::: "memory"); \
    __builtin_amdgcn_sched_barrier(0);

#define COMP1(aa, btj, spv, vvv, pout)                                        \
    {                                                                         \
        const float z = (aa) + (btj);                                         \
        const int pred = (z > 0.0f) ? 1 : 0;                                  \
        (pout) = pred ? 1.0f : 0.0f;                                          \
        tpc += ((spv) == 1) & pred;                                           \
        tnc += ((spv) == 1) & (pred ^ 1);                                     \
        fpc += ((spv) == 0) & ((vvv) == 1) & pred;                            \
        vc  += (vvv);                                                         \
        const float t = ((spv) == 1) ? z : -z;                                \
        const float u = __expf(-t);                                           \
        const float d = 1.0f + u;                                             \
        const float m = u * __builtin_amdgcn_rcpf(d);                         \
        const float fl = 0.5f * m * m * __logf(d);                            \
        ls += (vvv) ? fl : 0.0f;                                              \
    }

#define COMPUTE(SPX, VVX, AVX, POX)            \
    COMP1(AVX, bt.x, SPX.x, VVX.x, POX.x)      \
    COMP1(AVX, bt.y, SPX.y, VVX.y, POX.y)      \
    COMP1(AVX, bt.z, SPX.z, VVX.z, POX.z)      \
    COMP1(AVX, bt.w, SPX.w, VVX.w, POX.w)

    // ---- prologue: [bt, sp0,vv0, sp1,vv1, av0, av1, sp2,vv2] ----
    LD_BT()
    LD_SPVV(sp0, vv0)          // sp/vv(0) @ 0
    LD_SPVV(sp1, vv1)          // sp/vv(1) @ 4096
    LD_AV(av0, "0")            // av(0)
    LD_AV(av1, "8")            // av(1)
    LD_SPVV(sp2, vv2)          // sp/vv(2) @ 8192 ; voff_pf -> 12288

    // ---- 16 stages; slot = s%3 (sp/vv/po), s&1 (av) ----
#define STAGE_MID(KSTR, SPX, VVX, AVX, POX, AOFF)  \
    WAITK(KSTR)                                    \
    COMPUTE(SPX, VVX, AVX, POX)                    \
    LD_AV(AVX, AOFF)                               \
    LD_SPVV(SPX, VVX)                              \
    ST_OUT(POX)

    STAGE_MID("3", sp0, vv0, av0, po0, "16")   // s=0  loads av(2), sp/vv(3)
    STAGE_MID("6", sp1, vv1, av1, po1, "24")   // s=1
    STAGE_MID("7", sp2, vv2, av0, po2, "32")   // s=2
    STAGE_MID("7", sp0, vv0, av1, po0, "40")   // s=3
    STAGE_MID("7", sp1, vv1, av0, po1, "48")   // s=4
    STAGE_MID("7", sp2, vv2, av1, po2, "56")   // s=5
    STAGE_MID("7", sp0, vv0, av0, po0, "64")   // s=6
    STAGE_MID("7", sp1, vv1, av1, po1, "72")   // s=7
    STAGE_MID("7", sp2, vv2, av0, po2, "80")   // s=8
    STAGE_MID("7", sp0, vv0, av1, po0, "88")   // s=9
    STAGE_MID("7", sp1, vv1, av0, po1, "96")   // s=10
    STAGE_MID("7", sp2, vv2, av1, po2, "104")  // s=11
    STAGE_MID("7", sp0, vv0, av0, po0, "112")  // s=12 loads av(14), sp/vv(15)

    // s=13: av(15) load, no sp/vv
    WAITK("7")
    COMPUTE(sp1, vv1, av1, po1)
    LD_AV(av1, "120")
    ST_OUT(po1)

    // s=14: no loads
    WAITK("5")
    COMPUTE(sp2, vv2, av0, po2)
    ST_OUT(po2)

    // s=15
    WAITK("2")
    COMPUTE(sp0, vv0, av1, po0)
    ST_OUT(po0)

    asm volatile("s_waitcnt vmcnt(0)" ::: "memory");
    __builtin_amdgcn_sched_barrier(0);

#undef STAGE_MID
#undef COMPUTE
#undef COMP1
#undef WAITK
#undef ST_OUT
#undef LD_AV
#undef LD_SPVV
#undef LD_BT

    // wave (64-lane) reduction
    for (int off = 32; off; off >>= 1) {
        tpc += __shfl_down(tpc, off);
        tnc += __shfl_down(tnc, off);
        fpc += __shfl_down(fpc, off);
        vc  += __shfl_down(vc,  off);
        ls  += __shfl_down(ls,  off);
    }

    __shared__ int   si[4][4];
    __shared__ float sf[4];
    const int wave = tid >> 6, lane = tid & 63;
    if (lane == 0) {
        si[wave][0] = tpc; si[wave][1] = tnc; si[wave][2] = fpc; si[wave][3] = vc;
        sf[wave] = ls;
    }
    __syncthreads();
    if (tid == 0) {
        int t0 = 0, t1 = 0, t2 = 0, t3 = 0;
        float f = 0.0f;
        for (int w = 0; w < 4; ++w) {
            t0 += si[w][0]; t1 += si[w][1]; t2 += si[w][2]; t3 += si[w][3];
            f += sf[w];
        }
        float* dst = pb + blockIdx.x * 8;
        dst[0] = (float)t0;
        dst[1] = (float)t1;
        dst[2] = (float)t2;
        dst[3] = (float)t3;
        dst[4] = f;
    }
}

// ---------------------------------------------------------------------------
// Kernel 3: unchanged.
// ---------------------------------------------------------------------------
__global__ __launch_bounds__(256) void k_fin(
    const float* __restrict__ pb, const float* __restrict__ se_part,
    const int* __restrict__ seqlen, float* __restrict__ out5)
{
    const int tid = threadIdx.x;
    long long t0 = 0, t1 = 0, t2 = 0, t3 = 0;
    float f = 0.0f, se = 0.0f;

    for (int i = tid; i < SPAN_BLOCKS; i += 256) {
        const float4 p0 = *(const float4*)(pb + i * 8);
        const float  p4 = pb[i * 8 + 4];
        t0 += (long long)p0.x; t1 += (long long)p0.y;
        t2 += (long long)p0.z; t3 += (long long)p0.w;
        f  += p4;
    }
    for (int i = tid; i < PREP_BLOCKS; i += 256) se += se_part[i];

    for (int off = 32; off; off >>= 1) {
        t0 += __shfl_down(t0, off);
        t1 += __shfl_down(t1, off);
        t2 += __shfl_down(t2, off);
        t3 += __shfl_down(t3, off);
        f  += __shfl_down(f,  off);
        se += __shfl_down(se, off);
    }

    __shared__ long long sl[4][4];
    __shared__ float sfl[4][2];
    const int wave = tid >> 6, lane = tid & 63;
    if (lane == 0) {
        sl[wave][0] = t0; sl[wave][1] = t1; sl[wave][2] = t2; sl[wave][3] = t3;
        sfl[wave][0] = f; sfl[wave][1] = se;
    }
    __syncthreads();
    if (tid == 0) {
        long long a0 = 0, a1 = 0, a2 = 0, a3 = 0;
        float af = 0.0f, ase = 0.0f;
        for (int w = 0; w < 4; ++w) {
            a0 += sl[w][0]; a1 += sl[w][1]; a2 += sl[w][2]; a3 += sl[w][3];
            af += sfl[w][0]; ase += sfl[w][1];
        }
        int ssum = 0;
        for (int i = 0; i < Bsz; ++i) ssum += seqlen[i];
        out5[0] = (float)a0;
        out5[1] = (float)a1;
        out5[2] = (float)a2;
        out5[3] = ase / (2.0f * Ll * (float)ssum);
        out5[4] = af / ((float)a3 + 1e-6f);
    }
}

extern "C" void kernel_launch(void* const* d_in, const int* in_sizes, int n_in,
                              void* d_out, int out_size, void* d_ws, size_t ws_size,
                              hipStream_t stream) {
    const float* x      = (const float*)d_in[0];
    const float* start  = (const float*)d_in[1];
    const float* end    = (const float*)d_in[2];
    const int*   span   = (const int*)d_in[3];
    const int*   val    = (const int*)d_in[4];
    const int*   seqlen = (const int*)d_in[5];
    const float* W_se   = (const float*)d_in[6];
    const float* b_se   = (const float*)d_in[7];
    const float* W_span = (const float*)d_in[8];
    const float* b_span = (const float*)d_in[9];

    float* out = (float*)d_out;

    const size_t n_at = (size_t)Bsz * Ll * Nn;    // 65536
    float* At      = (float*)d_ws;
    float* Bt      = At + n_at;
    float* se_part = Bt + n_at;
    float* pb      = se_part + PREP_BLOCKS;

    k_prep<<<PREP_BLOCKS, 256, 0, stream>>>(x, start, end, seqlen,
                                            W_se, b_se, W_span, b_span,
                                            At, Bt, se_part);

    k_span<<<SPAN_BLOCKS, 256, 0, stream>>>(At, Bt, span, val, out, pb);

    k_fin<<<1, 256, 0, stream>>>(pb, se_part, seqlen, out + (long long)Bsz * Ll * Nn * Nn);
}